// Round 7
// baseline (340.338 us; speedup 1.0000x reference)
//
#include <hip/hip_runtime.h>
#include <hip/hip_bf16.h>

// RelativeAttention B=2,N=1024,C=512,H=8,HD=64 — round 6: tr_b16 X2.
//  attn: grid 512 = b(2) x itile(64) x jsplit(4); 512 thr = 8 waves = heads;
//  LDS 55KB -> 2 blocks/CU. rpb tile stored subtiled [i][cb][p(j)][16c] with
//  j-rows bit2<->bit3 swapped so ds_read_b64_tr_b16 pairs deliver X2's
//  B-fragments directly (replaces 64 ds_read_u16 + ~130 VALU pack ops per
//  lane per iter). S2 reads adjusted to subtiled layout. P[8][17][40]
//  (i-pad 17 fixes pa2 16-way bank conflict). S2s[16][8][20] (aligned b128).
// ws: qh 2MB | kh 2MB | vhT 2MB | xpart 16MB | lsum 256KB | xb 4MB

typedef __attribute__((ext_vector_type(8))) short short8;
typedef __attribute__((ext_vector_type(4))) float f32x4;

__device__ __forceinline__ unsigned short f2b(float f) {
    union { float f; unsigned u; } v; v.f = f;
    unsigned r = (v.u + 0x7FFF + ((v.u >> 16) & 1)) >> 16;   // RNE
    return (unsigned short)r;
}

// v_cvt_pk_bf16_f32: dst = [bf16(b) | bf16(a)] (RNE), 1 VALU op
__device__ __forceinline__ unsigned cvt_pk(float a, float b) {
    unsigned r;
    asm("v_cvt_pk_bf16_f32 %0, %1, %2" : "=v"(r) : "v"(a), "v"(b));
    return r;
}

// hardware transpose read: 64b per lane, 16-bit elem transpose (gfx950)
#define TRR(D, VA, OFF)                                                        \
    asm volatile("ds_read_b64_tr_b16 %0, %1 offset:" #OFF                      \
                 : "=v"(D) : "v"(VA))

// ---------------------------------------------------------------------------
// GEMM: Y = X[2048,512] @ W[512,512]   (unchanged)
// ---------------------------------------------------------------------------
template <int MODE>
__global__ __launch_bounds__(256) void gemm512(
    const float* __restrict__ X, const float* __restrict__ W,
    const float* __restrict__ bias, float* __restrict__ Yf,
    unsigned short* __restrict__ Ybf, float scale)
{
    __shared__ float As[32][68];
    __shared__ float Bs[32][68];
    __shared__ float Ts[(MODE == 2) ? 64 : 1][65];
    const int t  = threadIdx.x;
    const int tx = t & 15, ty = t >> 4;
    const int m0 = blockIdx.x * 64;
    const int n0 = blockIdx.y * 64;

    float acc[4][4] = {};

    for (int k0 = 0; k0 < 512; k0 += 32) {
        #pragma unroll
        for (int l = 0; l < 2; l++) {
            int qi = t + l * 256;
            int r = qi >> 3, q = qi & 7;
            float4 av = *reinterpret_cast<const float4*>(
                X + (size_t)(m0 + r) * 512 + k0 + q * 4);
            As[q * 4 + 0][r] = av.x; As[q * 4 + 1][r] = av.y;
            As[q * 4 + 2][r] = av.z; As[q * 4 + 3][r] = av.w;
        }
        #pragma unroll
        for (int l = 0; l < 2; l++) {
            int qi = t + l * 256;
            int kk = qi >> 4, q = qi & 15;
            *reinterpret_cast<float4*>(&Bs[kk][q * 4]) =
                *reinterpret_cast<const float4*>(
                    W + (size_t)(k0 + kk) * 512 + n0 + q * 4);
        }
        __syncthreads();
        #pragma unroll
        for (int kk = 0; kk < 32; kk++) {
            float4 a4 = *reinterpret_cast<const float4*>(&As[kk][ty * 4]);
            float4 b4 = *reinterpret_cast<const float4*>(&Bs[kk][tx * 4]);
            float av[4] = {a4.x, a4.y, a4.z, a4.w};
            float bv[4] = {b4.x, b4.y, b4.z, b4.w};
            #pragma unroll
            for (int ii = 0; ii < 4; ii++)
                #pragma unroll
                for (int jj = 0; jj < 4; jj++)
                    acc[ii][jj] = fmaf(av[ii], bv[jj], acc[ii][jj]);
        }
        __syncthreads();
    }

    if (MODE == 0) {
        const int h = n0 >> 6;
        #pragma unroll
        for (int ii = 0; ii < 4; ii++) {
            int m = m0 + ty * 4 + ii;
            int bb = m >> 10, nn = m & 1023;
            ushort4 o;
            o.x = f2b(acc[ii][0] * scale); o.y = f2b(acc[ii][1] * scale);
            o.z = f2b(acc[ii][2] * scale); o.w = f2b(acc[ii][3] * scale);
            *reinterpret_cast<ushort4*>(
                Ybf + ((size_t)((bb * 8 + h) * 1024 + nn)) * 64 + tx * 4) = o;
        }
    } else if (MODE == 1) {
        float4 bv = *reinterpret_cast<const float4*>(bias + n0 + tx * 4);
        #pragma unroll
        for (int ii = 0; ii < 4; ii++) {
            int m = m0 + ty * 4 + ii;
            float4 o;
            o.x = acc[ii][0] + bv.x; o.y = acc[ii][1] + bv.y;
            o.z = acc[ii][2] + bv.z; o.w = acc[ii][3] + bv.w;
            *reinterpret_cast<float4*>(Yf + (size_t)m * 512 + n0 + tx * 4) = o;
        }
    } else {
        #pragma unroll
        for (int ii = 0; ii < 4; ii++)
            #pragma unroll
            for (int jj = 0; jj < 4; jj++)
                Ts[ty * 4 + ii][tx * 4 + jj] = acc[ii][jj];
        __syncthreads();
        const int h = n0 >> 6;
        const int bb = m0 >> 10, nn = m0 & 1023;
        const int rc = t >> 2, jc = t & 3;
        unsigned short tmp[16];
        #pragma unroll
        for (int q = 0; q < 16; q++) tmp[q] = f2b(Ts[jc * 16 + q][rc]);
        unsigned short* dst = Ybf + (((size_t)(bb * 8 + h) * 64 + rc) << 10) + nn + jc * 16;
        *reinterpret_cast<short8*>(dst)     = *reinterpret_cast<short8*>(&tmp[0]);
        *reinterpret_cast<short8*>(dst + 8) = *reinterpret_cast<short8*>(&tmp[8]);
    }
}

// ---------------------------------------------------------------------------
// attn: grid 512 = b(2) x itile(64) x jsplit(4); 512 thr = 8 waves = heads
// ---------------------------------------------------------------------------
__global__ __launch_bounds__(512, 4) void attn_mfma(
    const unsigned short* __restrict__ qhg, const unsigned short* __restrict__ khg,
    const unsigned short* __restrict__ vtg, const float* __restrict__ rpb,
    const float* __restrict__ mask, float* __restrict__ xpart,
    float* __restrict__ lsump)
{
    // subtiled: [i][cblk][p(j)][c16]; p(j) = j with bits 2,3 swapped.
    __shared__ unsigned short rpb_s[16][4][16][16];   // 32 KB
    __shared__ unsigned short P[8][17][40];           // 10.9 KB, j 16..39 ZERO
    __shared__ float S2s[16][8][20];                  // 12.5 KB (b128-aligned)

    const int bid = blockIdx.x;
    const int js = bid & 3, it = (bid >> 2) & 63, b = bid >> 8;
    const int i0 = it * 16, jb = js * 256;
    const int t = threadIdx.x, w = t >> 6, l = t & 63;
    const int lg = l >> 4, l16 = l & 15;

    // staging map: per half 0/1, itr 0..1: (i = sib+4*(2*half+itr), j = sj, c = sc..+7)
    const int sj = (t >> 3) & 15, sc = (t & 7) * 8, sib = t >> 7;
    const int spj = (sj & 3) | ((sj & 4) << 1) | ((sj & 8) >> 1);  // bit2<->3
    const int scb = sc >> 4, sco = sc & 15;
    const int pl16 = (l16 & 3) | ((l16 & 4) << 1) | ((l16 & 8) >> 1);

    const float* rpbb = rpb + ((size_t)(b * 1024 + i0) << 16);
    const unsigned short* khb = khg + ((size_t)(b * 8 + w) << 16);
    const unsigned short* vtb = vtg + ((size_t)(b * 8 + w) << 16);
    const unsigned short* qhd = qhg + ((size_t)(b * 8) << 16);

    // 32-bit LDS byte offset of rpb_s for tr reads
    unsigned rs_base;
    {
        auto p3 = (__attribute__((address_space(3))) unsigned short*)&rpb_s[0][0][0][0];
        rs_base = (unsigned)(unsigned long long)p3;
    }

#define RPB_ISSUE(PF, J0)                                                      \
    _Pragma("unroll")                                                          \
    for (int itr = 0; itr < 4; ++itr) {                                        \
        const float4* s_ = reinterpret_cast<const float4*>(                    \
            rpbb + ((size_t)(sib + 4 * itr) << 16) +                           \
            (size_t)((J0) + sj) * 64 + sc);                                    \
        PF[itr] = s_[0]; PF[4 + itr] = s_[1];                                  \
    }
    // PF[itr] = c sc..sc+3 ; PF[4+itr] = c sc+4..sc+7 of row (i, j)

#define RPB_WRITE(PF)                                                          \
    _Pragma("unroll")                                                          \
    for (int itr = 0; itr < 4; ++itr) {                                        \
        float4 ua = PF[itr], ub = PF[4 + itr];                                 \
        uint4 pk;                                                              \
        pk.x = cvt_pk(ua.x, ua.y); pk.y = cvt_pk(ua.z, ua.w);                  \
        pk.z = cvt_pk(ub.x, ub.y); pk.w = cvt_pk(ub.z, ub.w);                  \
        *reinterpret_cast<uint4*>(&rpb_s[sib + 4 * itr][scb][spj][sco]) = pk;  \
    }

    // ---- prologue: zero P (incl. pad), stage tile 0 ----
    {
        unsigned short* P1 = &P[0][0][0];
        #pragma unroll
        for (int r = 0; r < 11; ++r) {
            int idx = t + 512 * r;
            if (idx < 5440) P1[idx] = 0;
        }
    }
    float mrow[4];
    #pragma unroll
    for (int r = 0; r < 4; r++) mrow[r] = mask[b * 1024 + i0 + lg * 4 + r];
    const int jo = (lg < 2) ? 8 * lg : 0;    // X1 zero-pad clamp

    float4 pf[8];
    RPB_ISSUE(pf, jb)
    RPB_WRITE(pf)
    __syncthreads();

    f32x4 x1[4];
    #pragma unroll
    for (int cs = 0; cs < 4; cs++) x1[cs] = 0.0f;
    f32x4 x2[2][4];
    #pragma unroll
    for (int il = 0; il < 2; il++)
        #pragma unroll
        for (int cg = 0; cg < 4; cg++) x2[il][cg] = 0.0f;
    float lsum[4] = {0.f, 0.f, 0.f, 0.f};

    for (int jt = 0; jt < 16; ++jt) {
        const int j0 = jb + jt * 16;

        // ---- top: issue all global loads for this iter (+ rpb for t+1) ----
        short8 kb0, kb1, a10, a11;
        {
            const unsigned short* kp = khb + (((size_t)(j0 + l16)) << 6) + 8 * lg;
            kb0 = *reinterpret_cast<const short8*>(kp);
            kb1 = *reinterpret_cast<const short8*>(kp + 32);
            const unsigned short* qp =
                qhd + ((size_t)w << 16) + (((size_t)(i0 + l16)) << 6) + 8 * lg;
            a10 = *reinterpret_cast<const short8*>(qp);
            a11 = *reinterpret_cast<const short8*>(qp + 32);
        }
        short8 bq[2][2];
        #pragma unroll
        for (int il = 0; il < 2; ++il) {
            const unsigned short* qp2 =
                qhd + ((size_t)(l16 & 7) << 16) + (((size_t)(i0 + 2 * w + il)) << 6) + 8 * lg;
            bq[il][0] = *reinterpret_cast<const short8*>(qp2);
            bq[il][1] = *reinterpret_cast<const short8*>(qp2 + 32);
        }
        float mj = mask[b * 1024 + j0 + l16];
        if (jt < 15) { RPB_ISSUE(pf, j0 + 16) }

        // ---- S1 = QK^T : D[16i x 16j], K=64 ----
        f32x4 C1; C1 = 0.0f;
        C1 = __builtin_amdgcn_mfma_f32_16x16x32_bf16(a10, kb0, C1, 0, 0, 0);
        C1 = __builtin_amdgcn_mfma_f32_16x16x32_bf16(a11, kb1, C1, 0, 0, 0);

        // ---- S2^T = rpb(A) @ q(B) : D[16j x 8h] per i, subtiled reads ----
        #pragma unroll
        for (int il = 0; il < 2; ++il) {
            int i = 2 * w + il;
            f32x4 D2; D2 = 0.0f;
            #pragma unroll
            for (int ch = 0; ch < 2; ++ch) {
                int cb = 2 * ch + (lg >> 1);
                int off16 = (lg & 1) * 8;
                short8 ar = *reinterpret_cast<const short8*>(
                    &rpb_s[i][cb][pl16][off16]);
                D2 = __builtin_amdgcn_mfma_f32_16x16x32_bf16(ar, bq[il][ch], D2, 0, 0, 0);
            }
            if (l16 < 8)
                *reinterpret_cast<f32x4*>(&S2s[i][l16][4 * lg]) = D2;
        }
        __syncthreads();                         // BAR1: S2s ready

        // ---- P = exp(S1 + S2 + pairmask) ----
        #pragma unroll
        for (int r = 0; r < 4; ++r) {
            int ir = lg * 4 + r;
            float mi = mrow[r];
            float pm = (fmaxf(mi, mj) < 0.f) ? 0.f : fminf(mi, mj);
            float s = C1[r] + S2s[ir][w][l16] + pm;
            float p = __expf(s);                  // bounded logits; -1e4 -> 0
            lsum[r] += p;
            P[w][ir][l16] = f2b(p);
        }
        __syncthreads();                         // BAR2: P ready

        // ---- X1 += P @ vhT : D[16i x 64c] (upper K zero via P) ----
        {
            short8 pa = *reinterpret_cast<const short8*>(&P[w][l16][8 * lg]);
            #pragma unroll
            for (int cs = 0; cs < 4; ++cs) {
                short8 vb = *reinterpret_cast<const short8*>(
                    vtb + ((size_t)(cs * 16 + l16) << 10) + j0 + jo);
                x1[cs] = __builtin_amdgcn_mfma_f32_16x16x32_bf16(pa, vb, x1[cs], 0, 0, 0);
            }
        }
        // ---- X2 += P(A) @ rpb(B) : D[8h x 16c] per i, tr_b16 B-frags ----
        #pragma unroll
        for (int il = 0; il < 2; ++il) {
            int i = 2 * w + il;
            unsigned va = rs_base + (unsigned)(i * 2048 + l * 8);
            unsigned long long d0, d1, d2, d3, d4, d5, d6, d7;
            TRR(d0, va, 0);    TRR(d1, va, 256);    // cg0: j 0-7 (via row swap)
            TRR(d2, va, 512);  TRR(d3, va, 768);    // cg1
            TRR(d4, va, 1024); TRR(d5, va, 1280);   // cg2
            TRR(d6, va, 1536); TRR(d7, va, 1792);   // cg3
            asm volatile("s_waitcnt lgkmcnt(0)" ::: "memory");
            __builtin_amdgcn_sched_barrier(0);
            short8 pa2 = *reinterpret_cast<const short8*>(&P[l16 & 7][i][8 * lg]);
            union TU { unsigned long long q[2]; short8 s; };
            TU u0, u1, u2, u3;
            u0.q[0] = d0; u0.q[1] = d1;
            u1.q[0] = d2; u1.q[1] = d3;
            u2.q[0] = d4; u2.q[1] = d5;
            u3.q[0] = d6; u3.q[1] = d7;
            x2[il][0] = __builtin_amdgcn_mfma_f32_16x16x32_bf16(pa2, u0.s, x2[il][0], 0, 0, 0);
            x2[il][1] = __builtin_amdgcn_mfma_f32_16x16x32_bf16(pa2, u1.s, x2[il][1], 0, 0, 0);
            x2[il][2] = __builtin_amdgcn_mfma_f32_16x16x32_bf16(pa2, u2.s, x2[il][2], 0, 0, 0);
            x2[il][3] = __builtin_amdgcn_mfma_f32_16x16x32_bf16(pa2, u3.s, x2[il][3], 0, 0, 0);
        }
        __syncthreads();                         // BAR3: tile-t reads done
        if (jt < 15) { RPB_WRITE(pf) }
        __syncthreads();                         // BAR4: tile t+1 staged
    }

    // ---- epilogue ----
    #pragma unroll
    for (int r = 0; r < 4; ++r) {
        float v = lsum[r];
        v += __shfl_xor(v, 1, 64); v += __shfl_xor(v, 2, 64);
        v += __shfl_xor(v, 4, 64); v += __shfl_xor(v, 8, 64);
        lsum[r] = v;
    }

    // redistribute x2 through LDS (reuse rpb_s = 32KB = [16i][8h][64c] f32)
    float* x2s = reinterpret_cast<float*>(&rpb_s[0][0][0][0]);
    if (lg < 2) {
        #pragma unroll
        for (int il = 0; il < 2; ++il)
            #pragma unroll
            for (int cg = 0; cg < 4; ++cg)
                #pragma unroll
                for (int r = 0; r < 4; ++r)
                    x2s[((2 * w + il) * 8 + 4 * lg + r) * 64 + cg * 16 + l16] =
                        x2[il][cg][r];
    }
    __syncthreads();

    #pragma unroll
    for (int cs = 0; cs < 4; ++cs)
        #pragma unroll
        for (int r = 0; r < 4; ++r) {
            int ir = lg * 4 + r;
            float val = x1[cs][r] + x2s[(ir * 8 + w) * 64 + cs * 16 + l16];
            xpart[((size_t)js << 20) + ((size_t)(b * 1024 + i0 + ir)) * 512
                  + w * 64 + cs * 16 + l16] = val;
        }
    if (l16 == 0) {
        #pragma unroll
        for (int r = 0; r < 4; ++r)
            lsump[((size_t)js << 14) + (b * 8 + w) * 1024 + i0 + lg * 4 + r] = lsum[r];
    }
#undef RPB_ISSUE
#undef RPB_WRITE
}

// ---------------------------------------------------------------------------
__global__ __launch_bounds__(256) void combine(
    const float* __restrict__ xpart, const float* __restrict__ lsump,
    float* __restrict__ xb)
{
    int idx4 = blockIdx.x * 256 + threadIdx.x;
    size_t base = (size_t)idx4 * 4;
    int row = (int)(base >> 9), col = (int)(base & 511);
    int bb = row >> 10, n = row & 1023, h = col >> 6;
    float ax = 0.f, ay = 0.f, az = 0.f, aw = 0.f, ls = 0.f;
    #pragma unroll
    for (int js = 0; js < 4; ++js) {
        float4 v = *reinterpret_cast<const float4*>(xpart + ((size_t)js << 20) + base);
        ax += v.x; ay += v.y; az += v.z; aw += v.w;
        ls += lsump[(js << 14) + (bb * 8 + h) * 1024 + n];
    }
    float inv = 1.f / ls;
    float4 o; o.x = ax * inv; o.y = ay * inv; o.z = az * inv; o.w = aw * inv;
    *reinterpret_cast<float4*>(xb + base) = o;
}

// ---------------------------------------------------------------------------
extern "C" void kernel_launch(void* const* d_in, const int* in_sizes, int n_in,
                              void* d_out, int out_size, void* d_ws, size_t ws_size,
                              hipStream_t stream)
{
    (void)in_sizes; (void)n_in; (void)out_size; (void)ws_size;
    const float* q    = (const float*)d_in[0];
    const float* k    = (const float*)d_in[1];
    const float* v    = (const float*)d_in[2];
    const float* rpb  = (const float*)d_in[3];
    const float* mask = (const float*)d_in[4];
    const float* Wq   = (const float*)d_in[5];
    const float* Wk   = (const float*)d_in[6];
    const float* Wv   = (const float*)d_in[7];
    const float* Wp   = (const float*)d_in[8];
    const float* bp   = (const float*)d_in[9];
    float* out = (float*)d_out;

    unsigned short* qhb = (unsigned short*)d_ws;     // bf16 [2,8,1024,64]
    unsigned short* khb = qhb + 1048576;
    unsigned short* vtb = khb + 1048576;             // bf16 [2,8,64,1024]
    float* xpart = (float*)(vtb + 1048576);          // [4][2048][512]
    float* lsump = xpart + 4194304;                  // [4][16384]
    float* xb    = lsump + 65536;                    // [2048][512]

    dim3 gg(32, 8, 1);
    gemm512<0><<<gg, 256, 0, stream>>>(q, Wq, nullptr, nullptr, qhb, 0.125f);
    gemm512<0><<<gg, 256, 0, stream>>>(k, Wk, nullptr, nullptr, khb, 1.0f);
    gemm512<2><<<gg, 256, 0, stream>>>(v, Wv, nullptr, nullptr, vtb, 1.0f);

    attn_mfma<<<512, 512, 0, stream>>>(qhb, khb, vtb, rpb, mask, xpart, lsump);

    combine<<<1024, 256, 0, stream>>>(xpart, lsump, xb);

    gemm512<1><<<gg, 256, 0, stream>>>(xb, Wp, bp, out, nullptr, 1.0f);
}